// Round 18
// baseline (118.739 us; speedup 1.0000x reference)
//
#include <hip/hip_runtime.h>
#include <hip/hip_bf16.h>
#include <math.h>

// ---------------------------------------------------------------------------
// SupConLoss on MI355X.
// out = 0.5*CE(predicts,targets) + 0.5*nt_xent(Anorm, temp=0.1)
//       + 0.25*nt_xent2(Anorm, temp=0.05)
// Round 18: round-17 structure; gemm K-quarter loop made COMPILE-TIME
// (template<KBQ=6>) and fully unrolled so all 48 independent operand loads
// hoist above the MFMA block -> one vmcnt wait per wave instead of six.
// (Round 13's hand-rotated buffers failed because of dynamic indexing; full
// unroll with constant offsets is the compiler-native form of the same
// pipeline.) Everything else unchanged from round 17 (best: 118.4 us).
// NOTE: ~42 us of total is the harness's 268 MB d_ws re-poison fill — fixed
// cost at 80% HBM peak, not addressable from kernel code.
// Exp sums unshifted (|exponent|<=20, fp32-safe); reference row-max shift
// applied exactly in merge: S_j = s2_raw * exp(-20*vmax_j).
// ---------------------------------------------------------------------------

typedef __attribute__((ext_vector_type(4))) float f32x4;
typedef long long ll;

__device__ __forceinline__ float blockReduceSum(float v, float* sbuf) {
#pragma unroll
  for (int o = 32; o > 0; o >>= 1) v += __shfl_down(v, o, 64);
  int lane = threadIdx.x & 63;
  int w = threadIdx.x >> 6;
  __syncthreads();
  if (lane == 0) sbuf[w] = v;
  __syncthreads();
  return sbuf[0] + sbuf[1] + sbuf[2] + sbuf[3];
}

// --- 1. normalize + fp8 fragment-pack + CE, wave-per-row; blk0 histogram ---
__global__ void k_prep(const float* __restrict__ X, const float* __restrict__ P,
                       const int* __restrict__ tgt, uint2* __restrict__ Pk,
                       float* __restrict__ ce_row, int* __restrict__ classCnt,
                       int N, int D, int C) {
  const int lane = threadIdx.x & 63;
  const int w = threadIdx.x >> 6;
  const int row = blockIdx.x * 4 + w;

  const float* x = X + (size_t)row * D;
  const float4* x4 = (const float4*)x;
  float ss = 0.f;
  for (int j = lane; j < (D >> 2); j += 64) {
    float4 v = x4[j];
    ss += v.x * v.x + v.y * v.y + v.z * v.z + v.w * v.w;
  }
#pragma unroll
  for (int o = 1; o < 64; o <<= 1) ss += __shfl_xor(ss, o, 64);
  float inv = 1.0f / fmaxf(sqrtf(ss), 1e-12f);

  const int KB = D / 32;           // 24
  const int strip = row >> 6;
  const int mt = (row >> 4) & 3;
  const int l4 = row & 15;
  const int nchunk = D / 8;        // 96
  for (int c = lane; c < nchunk; c += 64) {
    int kb = c >> 2;
    int lsub = c & 3;
    int k0 = kb * 32 + lsub * 8;
    float4 v0 = x4[k0 >> 2];
    float4 v1 = x4[(k0 >> 2) + 1];
    unsigned int r0 = 0, r1 = 0;
    r0 = __builtin_amdgcn_cvt_pk_fp8_f32(v0.x * inv, v0.y * inv, r0, 0);
    r0 = __builtin_amdgcn_cvt_pk_fp8_f32(v0.z * inv, v0.w * inv, r0, 1);
    r1 = __builtin_amdgcn_cvt_pk_fp8_f32(v1.x * inv, v1.y * inv, r1, 0);
    r1 = __builtin_amdgcn_cvt_pk_fp8_f32(v1.z * inv, v1.w * inv, r1, 1);
    int plane = l4 + 16 * lsub;
    size_t chunk = ((size_t)(strip * KB + kb) * 4 + mt) * 64 + plane;
    Pk[chunk] = make_uint2(r0, r1);
  }
  if (lane == 0) {
    const float* p = P + (size_t)row * C;
    float m = -INFINITY;
    for (int c = 0; c < C; ++c) m = fmaxf(m, p[c]);
    float s = 0.f;
    for (int c = 0; c < C; ++c) s += expf(p[c] - m);
    int t = tgt[row];
    ce_row[row] = -(p[t] - m - logf(s));
  }
  if (blockIdx.x == 0) {
    __shared__ int hc[32];
    if (threadIdx.x < 32) hc[threadIdx.x] = 0;
    __syncthreads();
    for (int i = threadIdx.x; i < N; i += blockDim.x)
      atomicAdd(&hc[tgt[i]], 1);
    __syncthreads();
    if (threadIdx.x < C) classCnt[threadIdx.x] = hc[threadIdx.x];
  }
}

// --- 2. 4-wave split-K 64x64 fused symmetric GEMM + stats, fp8 packed ------
// KBQ > 0: compile-time K-quarter count (fully unrolled loads hoist).
template <int KBQ>
__global__ __launch_bounds__(256) void k_gemm_fused(
    const unsigned char* __restrict__ Pk, const int* __restrict__ lab,
    float4* __restrict__ part, int N, int K, int NB, int kbq_rt) {
  __shared__ f32x4 buf0[4][4][64];  // 16 KB
  __shared__ f32x4 buf1[4][4][64];  // 16 KB

  int bid = blockIdx.x;
  int by = (int)((sqrtf(8.f * (float)bid + 1.f) - 1.f) * 0.5f);
  while ((by + 1) * (by + 2) / 2 <= bid) ++by;
  while (by * (by + 1) / 2 > bid) --by;
  int bx = bid - by * (by + 1) / 2;

  const int t = threadIdx.x & 63;
  const int wv = threadIdx.x >> 6;  // 0..3
  const int rowBase = by * 64;
  const int colBase = bx * 64;
  const int KB = K / 32;
  const int KBq = (KBQ > 0) ? KBQ : kbq_rt;

  const int myLR = lab[rowBase + t];
  const int myLC = lab[colBase + t];

  const unsigned char* aP =
      Pk + ((size_t)by * KB * 4 * 64 + t) * 8 + (size_t)wv * KBq * 2048;
  const unsigned char* bP =
      Pk + ((size_t)bx * KB * 4 * 64 + t) * 8 + (size_t)wv * KBq * 2048;

  f32x4 acc[4][4] = {};
#pragma unroll
  for (int kb = 0; kb < KBq; ++kb) {
    ll af[4], bf[4];
    const unsigned char* ak = aP + (size_t)kb * 2048;
    const unsigned char* bk = bP + (size_t)kb * 2048;
#pragma unroll
    for (int mt = 0; mt < 4; ++mt) af[mt] = *(const ll*)(ak + mt * 512);
#pragma unroll
    for (int nt = 0; nt < 4; ++nt) bf[nt] = *(const ll*)(bk + nt * 512);
#pragma unroll
    for (int mt = 0; mt < 4; ++mt)
#pragma unroll
      for (int nt = 0; nt < 4; ++nt)
        acc[mt][nt] = __builtin_amdgcn_mfma_f32_16x16x32_fp8_fp8(
            af[mt], bf[nt], acc[mt][nt], 0, 0, 0);
  }

  // ---- 2-step tree exchange: buf0 = w0+w1, buf1 = w2+w3 ------------------
  if (wv == 0) {
#pragma unroll
    for (int mt = 0; mt < 4; ++mt)
#pragma unroll
      for (int nt = 0; nt < 4; ++nt) buf0[mt][nt][t] = acc[mt][nt];
  } else if (wv == 2) {
#pragma unroll
    for (int mt = 0; mt < 4; ++mt)
#pragma unroll
      for (int nt = 0; nt < 4; ++nt) buf1[mt][nt][t] = acc[mt][nt];
  }
  __syncthreads();
  if (wv == 1) {
#pragma unroll
    for (int mt = 0; mt < 4; ++mt)
#pragma unroll
      for (int nt = 0; nt < 4; ++nt) {
        acc[mt][nt] += buf0[mt][nt][t];
        buf0[mt][nt][t] = acc[mt][nt];
      }
  } else if (wv == 3) {
#pragma unroll
    for (int mt = 0; mt < 4; ++mt)
#pragma unroll
      for (int nt = 0; nt < 4; ++nt) {
        acc[mt][nt] += buf1[mt][nt][t];
        buf1[mt][nt][t] = acc[mt][nt];
      }
  }
  __syncthreads();

  // ---- epilogue: w0/w1 = A-side (mt pairs), w2/w3 = B-side (nt pairs) -----
  int cl[4];
#pragma unroll
  for (int nt = 0; nt < 4; ++nt) cl[nt] = __shfl(myLC, nt * 16 + (t & 15), 64);
  const bool dg = (by == bx);

  if (wv < 2) {
    f32x4 fq[2][4];
#pragma unroll
    for (int mi = 0; mi < 2; ++mi) {
      int mt = wv * 2 + mi;
#pragma unroll
      for (int nt = 0; nt < 4; ++nt)
        fq[mi][nt] = buf0[mt][nt][t] + buf1[mt][nt][t];
    }
#pragma unroll
    for (int mi = 0; mi < 2; ++mi) {
      int mt = wv * 2 + mi;
#pragma unroll
      for (int r = 0; r < 4; ++r) {
        int rowL = mt * 16 + (t >> 4) * 4 + r;
        int lr = __shfl(myLR, rowL, 64);
        float ps = 0.f, s1 = 0.f, s2 = 0.f, vm = -1e30f;
#pragma unroll
        for (int nt = 0; nt < 4; ++nt) {
          float v = fq[mi][nt][r];
          int colL = nt * 16 + (t & 15);
          bool diag = dg && (rowL == colL);
          bool same = (lr == cl[nt]);
          float e10 = __expf(v * 10.f);
          float e20 = e10 * e10;
          s1 += diag ? 1.f : e10;
          ps += (same && !diag) ? v : 0.f;
          s2 += same ? 0.f : e20;
          vm = same ? vm : fmaxf(vm, v);
        }
#pragma unroll
        for (int o = 1; o < 16; o <<= 1) {
          ps += __shfl_xor(ps, o, 64);
          s1 += __shfl_xor(s1, o, 64);
          s2 += __shfl_xor(s2, o, 64);
          vm = fmaxf(vm, __shfl_xor(vm, o, 64));
        }
        if ((t & 15) == 0)
          part[(size_t)(rowBase + rowL) * NB + bx] =
              make_float4(ps, s1, s2, 20.f * vm);
      }
    }
  } else if (!dg) {
    f32x4 fq[4][2];
#pragma unroll
    for (int ni = 0; ni < 2; ++ni) {
      int nt = (wv - 2) * 2 + ni;
#pragma unroll
      for (int mt = 0; mt < 4; ++mt)
        fq[mt][ni] = buf0[mt][nt][t] + buf1[mt][nt][t];
    }
#pragma unroll
    for (int ni = 0; ni < 2; ++ni) {
      int nt = (wv - 2) * 2 + ni;
      int lc = cl[nt];
      float ps = 0.f, s1 = 0.f, s2 = 0.f, vm = -1e30f;
#pragma unroll
      for (int mt = 0; mt < 4; ++mt)
#pragma unroll
        for (int r = 0; r < 4; ++r) {
          float v = fq[mt][ni][r];
          int rowL = mt * 16 + (t >> 4) * 4 + r;
          int lr = __shfl(myLR, rowL, 64);
          bool same = (lr == lc);
          float e10 = __expf(v * 10.f);
          s1 += e10;
          ps += same ? v : 0.f;
          s2 += same ? 0.f : e10 * e10;
          vm = same ? vm : fmaxf(vm, v);
        }
#pragma unroll
      for (int o = 16; o < 64; o <<= 1) {
        ps += __shfl_xor(ps, o, 64);
        s1 += __shfl_xor(s1, o, 64);
        s2 += __shfl_xor(s2, o, 64);
        vm = fmaxf(vm, __shfl_xor(vm, o, 64));
      }
      if ((t >> 4) == 0)
        part[(size_t)(colBase + nt * 16 + (t & 15)) * NB + by] =
            make_float4(ps, s1, s2, 20.f * vm);
    }
  }
}

// --- 3. merge partials per row -> per-block partial sums (plain stores) ----
__global__ void k_merge(const float4* __restrict__ part,
                        const float* __restrict__ ce_row,
                        const int* __restrict__ lab,
                        const int* __restrict__ classCnt,
                        float2* __restrict__ partial2,
                        float* __restrict__ partialS, int N, int NB, int C) {
  __shared__ float srowA[4], ceA[4], p1A[4];
  __shared__ int labA[4];
  int lane = threadIdx.x & 63;
  int w = threadIdx.x >> 6;
  int row = blockIdx.x * 4 + w;
  float ps = 0.f, s1 = 0.f, s2 = 0.f, m2 = -1e30f;
  if (lane < NB) {
    float4 p = part[(size_t)row * NB + lane];
    ps = p.x; s1 = p.y; s2 = p.z; m2 = p.w;
  }
#pragma unroll
  for (int o = 32; o > 0; o >>= 1) {
    ps += __shfl_down(ps, o, 64);
    s1 += __shfl_down(s1, o, 64);
    s2 += __shfl_down(s2, o, 64);
    m2 = fmaxf(m2, __shfl_down(m2, o, 64));
  }
  if (lane == 0) {
    int l = lab[row];
    float Srow = (m2 < -1e29f) ? 0.f : s2 * expf(-m2);
    int pc = classCnt[l] - 1;
    float p1 = (pc > 0) ? ps * 10.f / (float)pc - logf(s1) : 0.f;
    srowA[w] = Srow;
    labA[w] = l;
    ceA[w] = ce_row[row];
    p1A[w] = p1;
  }
  __syncthreads();
  int t = threadIdx.x;
  if (t < C) {
    float s = 0.f;
#pragma unroll
    for (int i = 0; i < 4; ++i) s += (labA[i] == t) ? srowA[i] : 0.f;
    partialS[blockIdx.x * 16 + t] = s;
  } else if (t == 16) {
    partial2[blockIdx.x] = make_float2(ceA[0] + ceA[1] + ceA[2] + ceA[3],
                                       p1A[0] + p1A[1] + p1A[2] + p1A[3]);
  }
}

// --- 4. finalize: reduce 1024x(2+10) partials + formula --------------------
__global__ void k_final(const float2* __restrict__ partial2,
                        const float* __restrict__ partialS,
                        const int* __restrict__ classCnt,
                        float* __restrict__ out, int NBLK, int N, int C) {
  __shared__ float sbuf[8];
  __shared__ float cls[32];
  float ce = 0.f, p1 = 0.f;
  for (int b = threadIdx.x; b < NBLK; b += blockDim.x) {
    float2 v = partial2[b];
    ce += v.x;
    p1 += v.y;
  }
  ce = blockReduceSum(ce, sbuf);
  p1 = blockReduceSum(p1, sbuf);
  for (int c = 0; c < C; ++c) {
    float s = 0.f;
    for (int b = threadIdx.x; b < NBLK; b += blockDim.x)
      s += partialS[b * 16 + c];
    s = blockReduceSum(s, sbuf);
    if (threadIdx.x == 0) cls[c] = s;
  }
  __syncthreads();
  if (threadIdx.x == 0) {
    float totS = 0.f;
    for (int c = 0; c < C; ++c) totS += cls[c];
    float l2sum = 0.f;
    for (int c = 0; c < C; ++c) {
      int cnt = classCnt[c];
      if (cnt >= 2) {
        float negs = (float)(N - cnt);
        float x = (totS - cls[c]) / negs;
        l2sum += (float)cnt * logf(x + 1e-12f);
      }
    }
    float cem = ce / (float)N;
    float ntx1 = -p1 / (float)N;
    float ntx2 = l2sum / (float)N;
    out[0] = 0.5f * cem + 0.5f * ntx1 + 0.25f * ntx2;
  }
}

extern "C" void kernel_launch(void* const* d_in, const int* in_sizes, int n_in,
                              void* d_out, int out_size, void* d_ws,
                              size_t ws_size, hipStream_t stream) {
  const float* X = (const float*)d_in[0];  // cls_feats [N,D]
  const float* P = (const float*)d_in[1];  // predicts  [N,C]
  const int* tgt = (const int*)d_in[2];    // targets   [N]
  float* out = (float*)d_out;

  int N = in_sizes[2];
  int D = in_sizes[0] / N;
  int C = in_sizes[1] / N;
  int NB = N / 64;
  int NBLK = N / 4;
  int KBq = D / 32 / 4;  // 6 for D=768

  char* ws = (char*)d_ws;
  uint2* Pk = (uint2*)ws;                        // N*D fp8 bytes, packed
  float4* part = (float4*)(ws + (size_t)N * D);  // N*NB float4
  float* ce_row = (float*)((char*)part + (size_t)N * NB * 16);
  int* classCnt = (int*)(ce_row + N);            // 32
  float2* partial2 = (float2*)(classCnt + 32);   // NBLK float2
  float* partialS = (float*)(partial2 + NBLK);   // NBLK*16 floats

  k_prep<<<NBLK, 256, 0, stream>>>(X, P, tgt, Pk, ce_row, classCnt, N, D, C);
  int nblk = NB * (NB + 1) / 2;
  if (KBq == 6) {
    k_gemm_fused<6><<<nblk, 256, 0, stream>>>((const unsigned char*)Pk, tgt,
                                              part, N, D, NB, KBq);
  } else {
    k_gemm_fused<0><<<nblk, 256, 0, stream>>>((const unsigned char*)Pk, tgt,
                                              part, N, D, NB, KBq);
  }
  k_merge<<<NBLK, 256, 0, stream>>>(part, ce_row, tgt, classCnt, partial2,
                                    partialS, N, NB, C);
  k_final<<<1, 256, 0, stream>>>(partial2, partialS, classCnt, out, NBLK, N,
                                 C);
}